// Round 1
// baseline (1348.544 us; speedup 1.0000x reference)
//
#include <hip/hip_runtime.h>
#include <math.h>

// Problem constants (fixed by setup_inputs)
#define BN    4096
#define DD    1024
#define CC    1000
#define MM    32768
#define ROWS_CAP 32768   // worst-case B + mem_ptr (mem_ptr <= M-B)

#define TILE 64
#define BKK  32

__device__ __forceinline__ float wave_max_f(float v) {
#pragma unroll
  for (int off = 32; off >= 1; off >>= 1) v = fmaxf(v, __shfl_xor(v, off, 64));
  return v;
}
__device__ __forceinline__ float wave_sum_f(float v) {
#pragma unroll
  for (int off = 32; off >= 1; off >>= 1) v += __shfl_xor(v, off, 64);
  return v;
}

// ---------------------------------------------------------------- row norms
__global__ __launch_bounds__(256) void rownorm_kernel(const float* __restrict__ x,
                                                      float* __restrict__ invn) {
  const int r = blockIdx.x;
  const float* p = x + (size_t)r * DD;
  const int t = threadIdx.x;
  float v0 = p[t], v1 = p[t + 256], v2 = p[t + 512], v3 = p[t + 768];
  float s = v0 * v0 + v1 * v1 + v2 * v2 + v3 * v3;
  s = wave_sum_f(s);
  __shared__ float part[4];
  if ((t & 63) == 0) part[t >> 6] = s;
  __syncthreads();
  if (t == 0) invn[r] = rsqrtf(part[0] + part[1] + part[2] + part[3] + 1e-24f);
}

// ---------------------------------------------------------------- class counts
__global__ __launch_bounds__(256) void count_kernel(const int* __restrict__ labels,
                                                    int* __restrict__ counts) {
  const int c = blockIdx.x * 256 + threadIdx.x;
  if (c >= CC) return;
  const int b0 = blockIdx.y * 256;
  int s = 0;
  for (int b = b0; b < b0 + 256; ++b) s += labels[(size_t)b * CC + c];
  atomicAdd(&counts[c], s);
}

// ---------------------------------------------------------------- class weights
__global__ __launch_bounds__(1024) void weights_kernel(const int* __restrict__ counts,
                                                       float* __restrict__ weights) {
  const int t = threadIdx.x;
  float w = 0.f;
  if (t < CC) {
    float cnt = (float)counts[t];
    float en = 1.0f - expf(cnt * logf(0.999f));   // 1 - BETA^cnt
    w = (1.0f - 0.999f) / (en + 1e-8f);
  }
  float s = wave_sum_f(w);
  __shared__ float part[16];
  if ((t & 63) == 0) part[t >> 6] = s;
  __syncthreads();
  float tot = 0.f;
#pragma unroll
  for (int i = 0; i < 16; ++i) tot += part[i];
  if (t < CC) weights[t] = w * ((float)CC / tot);
}

// ---------------------------------------------------------------- fp32 GEMM chunk
// sim[r - chunk_lo][c] = dot(feat_r_normalized, z_prompt_c) / TEMPERATURE
__global__ __launch_bounds__(256) void gemm_chunk(
    const float* __restrict__ img, const float* __restrict__ mem,
    const float* __restrict__ prompts, const float* __restrict__ inv_img,
    const float* __restrict__ inv_p, const int* __restrict__ memptr,
    float* __restrict__ sim, int chunk_lo) {
  const int nrows = BN + memptr[0];
  const int row0 = chunk_lo + blockIdx.y * TILE;
  if (row0 >= nrows) return;
  const int c0 = blockIdx.x * TILE;

  __shared__ float As[BKK][TILE + 4];
  __shared__ float Bs[BKK][TILE + 4];

  const int t = threadIdx.x;
  const int lr = t >> 2;          // 0..63 : row/col within tile for loading
  const int lk = (t & 3) * 8;     // 0,8,16,24 : k offset for loading

  // A source for this thread's load row
  const int arow = row0 + lr;
  const float* aptr = nullptr;
  float ascale = 0.f;
  if (arow < BN) { aptr = img + (size_t)arow * DD; ascale = inv_img[arow]; }
  else if (arow < nrows) { aptr = mem + (size_t)(arow - BN) * DD; ascale = 1.f; }

  const int bcol = c0 + lr;
  const float* bptr = nullptr;
  float bscale = 0.f;
  if (bcol < CC) { bptr = prompts + (size_t)bcol * DD; bscale = inv_p[bcol]; }

  const int tr = t >> 4;   // 0..15
  const int tc = t & 15;   // 0..15
  float acc[4][4] = {};

  for (int k0 = 0; k0 < DD; k0 += BKK) {
    float4 a0 = {0,0,0,0}, a1 = {0,0,0,0}, b0 = {0,0,0,0}, b1 = {0,0,0,0};
    if (aptr) {
      a0 = *(const float4*)(aptr + k0 + lk);
      a1 = *(const float4*)(aptr + k0 + lk + 4);
    }
    if (bptr) {
      b0 = *(const float4*)(bptr + k0 + lk);
      b1 = *(const float4*)(bptr + k0 + lk + 4);
    }
    __syncthreads();
    As[lk + 0][lr] = a0.x * ascale; As[lk + 1][lr] = a0.y * ascale;
    As[lk + 2][lr] = a0.z * ascale; As[lk + 3][lr] = a0.w * ascale;
    As[lk + 4][lr] = a1.x * ascale; As[lk + 5][lr] = a1.y * ascale;
    As[lk + 6][lr] = a1.z * ascale; As[lk + 7][lr] = a1.w * ascale;
    Bs[lk + 0][lr] = b0.x * bscale; Bs[lk + 1][lr] = b0.y * bscale;
    Bs[lk + 2][lr] = b0.z * bscale; Bs[lk + 3][lr] = b0.w * bscale;
    Bs[lk + 4][lr] = b1.x * bscale; Bs[lk + 5][lr] = b1.y * bscale;
    Bs[lk + 6][lr] = b1.z * bscale; Bs[lk + 7][lr] = b1.w * bscale;
    __syncthreads();
#pragma unroll
    for (int kk = 0; kk < BKK; ++kk) {
      float4 av = *(const float4*)&As[kk][tr * 4];
      float4 bv = *(const float4*)&Bs[kk][tc * 4];
      acc[0][0] += av.x * bv.x; acc[0][1] += av.x * bv.y;
      acc[0][2] += av.x * bv.z; acc[0][3] += av.x * bv.w;
      acc[1][0] += av.y * bv.x; acc[1][1] += av.y * bv.y;
      acc[1][2] += av.y * bv.z; acc[1][3] += av.y * bv.w;
      acc[2][0] += av.z * bv.x; acc[2][1] += av.z * bv.y;
      acc[2][2] += av.z * bv.z; acc[2][3] += av.z * bv.w;
      acc[3][0] += av.w * bv.x; acc[3][1] += av.w * bv.y;
      acc[3][2] += av.w * bv.z; acc[3][3] += av.w * bv.w;
    }
  }

#pragma unroll
  for (int i = 0; i < 4; ++i) {
    int r = row0 + tr * 4 + i;
    if (r >= nrows) continue;
    size_t base = (size_t)(r - chunk_lo) * CC;
#pragma unroll
    for (int j = 0; j < 4; ++j) {
      int c = c0 + tc * 4 + j;
      if (c < CC) sim[base + c] = acc[i][j] * 10.0f;  // 1/TEMPERATURE
    }
  }
}

// ---------------------------------------------------------------- per-row epilogue
// One wave per row: top-10 negatives, masked LSE, weighted sums, atomic accumulate.
__global__ __launch_bounds__(256) void rowpost_kernel(
    const float* __restrict__ sim, const int* __restrict__ labels,
    const int* __restrict__ mlabels, const float* __restrict__ weights,
    const int* __restrict__ memptr, float* __restrict__ acc, int chunk_lo) {
  const int nrows = BN + memptr[0];
  const int wid = threadIdx.x >> 6;
  const int lane = threadIdx.x & 63;
  const int row = chunk_lo + blockIdx.x * 4 + wid;
  if (row >= nrows) return;

  const float* srow = sim + (size_t)(row - chunk_lo) * CC;
  const int* lrow = (row < BN) ? labels + (size_t)row * CC
                               : mlabels + (size_t)(row - BN) * CC;
  float sv[16];
  bool pv[16];
  float vneg[16];
#pragma unroll
  for (int j = 0; j < 16; ++j) {
    int c = lane + 64 * j;
    bool ok = (c < CC);
    float s = ok ? srow[c] : -INFINITY;
    bool p = ok && (lrow[c] > 0);
    sv[j] = s; pv[j] = p;
    vneg[j] = (ok && !p) ? s : -INFINITY;
  }

  // 10 rounds of max-extraction over negatives -> 10th largest negative
  float v10 = -INFINITY;
  for (int r = 0; r < 10; ++r) {
    float lm = -INFINITY;
#pragma unroll
    for (int j = 0; j < 16; ++j) lm = fmaxf(lm, vneg[j]);
    lm = wave_max_f(lm);
#pragma unroll
    for (int j = 0; j < 16; ++j) if (vneg[j] == lm) vneg[j] = -INFINITY;
    v10 = lm;
  }

  // masked LSE + weighted sums
  float mmax = -INFINITY;
#pragma unroll
  for (int j = 0; j < 16; ++j) {
    int c = lane + 64 * j;
    if (c < CC && (pv[j] || sv[j] >= v10)) mmax = fmaxf(mmax, sv[j]);
  }
  mmax = wave_max_f(mmax);

  float esum = 0.f, wsum = 0.f, wsim = 0.f;
#pragma unroll
  for (int j = 0; j < 16; ++j) {
    int c = lane + 64 * j;
    if (c < CC) {
      if (pv[j] || sv[j] >= v10) esum += expf(sv[j] - mmax);
      if (pv[j]) { float w = weights[c]; wsum += w; wsim += w * sv[j]; }
    }
  }
  esum = wave_sum_f(esum);
  wsum = wave_sum_f(wsum);
  wsim = wave_sum_f(wsim);

  if (lane == 0) {
    float lse = mmax + logf(esum);
    bool valid = (wsum > 0.f);
    float lps = valid ? (wsum * lse - wsim) / (wsum + 1e-8f) : 0.f;
    float mult = (row < BN) ? 2.f : 1.f;   // image rows appear twice in enhanced set
    atomicAdd(&acc[0], mult * lps);
    if (valid) atomicAdd(&acc[1], mult);
  }
}

// ---------------------------------------------------------------- finalize
__global__ void finalize_kernel(const float* __restrict__ acc, float* __restrict__ out) {
  out[0] = acc[0] / fmaxf(acc[1], 1.0f);
}

// ---------------------------------------------------------------- launcher
extern "C" void kernel_launch(void* const* d_in, const int* in_sizes, int n_in,
                              void* d_out, int out_size, void* d_ws, size_t ws_size,
                              hipStream_t stream) {
  const float* img     = (const float*)d_in[0];
  const float* prompts = (const float*)d_in[1];
  const int*   labels  = (const int*)d_in[2];
  const float* mem     = (const float*)d_in[3];
  const int*   mlabels = (const int*)d_in[4];
  const int*   memptr  = (const int*)d_in[5];
  float* out = (float*)d_out;
  char* ws = (char*)d_ws;

  float* acc     = (float*)(ws + 0);       // 2 floats
  int*   counts  = (int*)(ws + 256);       // CC ints
  float* weights = (float*)(ws + 4352);    // CC floats
  float* inv_p   = (float*)(ws + 8448);    // CC floats
  float* inv_img = (float*)(ws + 12544);   // BN floats
  float* sim     = (float*)(ws + 32768);   // chunk_rows x CC floats

  hipMemsetAsync(ws, 0, 4352, stream);     // zero acc + counts

  rownorm_kernel<<<CC, 256, 0, stream>>>(prompts, inv_p);
  rownorm_kernel<<<BN, 256, 0, stream>>>(img, inv_img);
  count_kernel<<<dim3((CC + 255) / 256, BN / 256), 256, 0, stream>>>(labels, counts);
  weights_kernel<<<1, 1024, 0, stream>>>(counts, weights);

  long long avail = (long long)ws_size - 32768;
  long long rowbytes = (long long)CC * 4;
  int chunk = (int)(avail / rowbytes);
  chunk &= ~63;
  if (chunk < 64) chunk = 64;
  if (chunk > ROWS_CAP) chunk = ROWS_CAP;

  for (int lo = 0; lo < ROWS_CAP; lo += chunk) {
    int rows = (ROWS_CAP - lo < chunk) ? (ROWS_CAP - lo) : chunk;
    dim3 g((CC + TILE - 1) / TILE, rows / TILE);
    gemm_chunk<<<g, 256, 0, stream>>>(img, mem, prompts, inv_img, inv_p, memptr, sim, lo);
    rowpost_kernel<<<rows / 4, 256, 0, stream>>>(sim, labels, mlabels, weights, memptr, acc, lo);
  }
  finalize_kernel<<<1, 1, 0, stream>>>(acc, out);
}

// Round 2
// 414.260 us; speedup vs baseline: 3.2553x; 3.2553x over previous
//
#include <hip/hip_runtime.h>
#include <math.h>

// Problem constants (fixed by setup_inputs)
#define BN    4096
#define DD    1024
#define CC    1000
#define MM    32768
#define ROWS_CAP 32768   // worst-case B + mem_ptr

typedef __attribute__((ext_vector_type(8))) short short8;
typedef __attribute__((ext_vector_type(4))) float f32x4;

__device__ __forceinline__ float wave_max_f(float v) {
#pragma unroll
  for (int off = 32; off >= 1; off >>= 1) v = fmaxf(v, __shfl_xor(v, off, 64));
  return v;
}
__device__ __forceinline__ float wave_sum_f(float v) {
#pragma unroll
  for (int off = 32; off >= 1; off >>= 1) v += __shfl_xor(v, off, 64);
  return v;
}

// round-to-nearest-even float -> bf16 bits (finite inputs)
__device__ __forceinline__ short f2bf(float f) {
  union { float f; unsigned u; } v; v.f = f;
  unsigned r = v.u + 0x7FFF + ((v.u >> 16) & 1);
  return (short)(r >> 16);
}

__device__ __forceinline__ void gload16(const short* g, short* l) {
  __builtin_amdgcn_global_load_lds(
      (const __attribute__((address_space(1))) unsigned int*)g,
      (__attribute__((address_space(3))) unsigned int*)l, 16, 0, 0);
}

// ---------------------------------------------------------------- row norms
__global__ __launch_bounds__(256) void rownorm_kernel(const float* __restrict__ x,
                                                      float* __restrict__ invn) {
  const int r = blockIdx.x;
  const float* p = x + (size_t)r * DD;
  const int t = threadIdx.x;
  float v0 = p[t], v1 = p[t + 256], v2 = p[t + 512], v3 = p[t + 768];
  float s = v0 * v0 + v1 * v1 + v2 * v2 + v3 * v3;
  s = wave_sum_f(s);
  __shared__ float part[4];
  if ((t & 63) == 0) part[t >> 6] = s;
  __syncthreads();
  if (t == 0) invn[r] = rsqrtf(part[0] + part[1] + part[2] + part[3] + 1e-24f);
}

// ---------------------------------------------------------------- class counts
__global__ __launch_bounds__(256) void count_kernel(const int* __restrict__ labels,
                                                    int* __restrict__ counts) {
  const int c = blockIdx.x * 256 + threadIdx.x;
  if (c >= CC) return;
  const int b0 = blockIdx.y * 256;
  int s = 0;
  for (int b = b0; b < b0 + 256; ++b) s += labels[(size_t)b * CC + c];
  atomicAdd(&counts[c], s);
}

// ---------------------------------------------------------------- class weights
__global__ __launch_bounds__(1024) void weights_kernel(const int* __restrict__ counts,
                                                       float* __restrict__ weights) {
  const int t = threadIdx.x;
  float w = 0.f;
  if (t < CC) {
    float cnt = (float)counts[t];
    float en = 1.0f - expf(cnt * logf(0.999f));   // 1 - BETA^cnt
    w = (1.0f - 0.999f) / (en + 1e-8f);
  }
  float s = wave_sum_f(w);
  __shared__ float part[16];
  if ((t & 63) == 0) part[t >> 6] = s;
  __syncthreads();
  float tot = 0.f;
#pragma unroll
  for (int i = 0; i < 16; ++i) tot += part[i];
  if (t < CC) weights[t] = w * ((float)CC / tot);
}

// ---------------------------------------------------------------- fp32 -> bf16 conversions
// B: prompts normalized, padded to 1024 rows x 1024
__global__ __launch_bounds__(256) void convB_kernel(const float* __restrict__ prompts,
                                                    const float* __restrict__ inv_p,
                                                    short* __restrict__ B) {
  const int gid = blockIdx.x * 256 + threadIdx.x;   // one per 8 elements
  const int row = gid >> 7;
  const int k8 = (gid & 127) * 8;
  short8 o = {0, 0, 0, 0, 0, 0, 0, 0};
  if (row < CC) {
    float sc = inv_p[row];
    const float4* s = (const float4*)(prompts + (size_t)row * DD + k8);
    float4 x = s[0], y = s[1];
    o[0] = f2bf(x.x * sc); o[1] = f2bf(x.y * sc);
    o[2] = f2bf(x.z * sc); o[3] = f2bf(x.w * sc);
    o[4] = f2bf(y.x * sc); o[5] = f2bf(y.y * sc);
    o[6] = f2bf(y.z * sc); o[7] = f2bf(y.w * sc);
  }
  *(short8*)(B + (size_t)row * DD + k8) = o;
}

// A: rows [lo, lo+rows): image rows normalized, memory rows raw, tail zero
__global__ __launch_bounds__(256) void convA_kernel(const float* __restrict__ img,
                                                    const float* __restrict__ mem,
                                                    const float* __restrict__ inv_img,
                                                    const int* __restrict__ memptr,
                                                    short* __restrict__ A, int lo) {
  const int nrows = BN + memptr[0];
  const int gid = blockIdx.x * 256 + threadIdx.x;
  const int rl = gid >> 7;
  const int k8 = (gid & 127) * 8;
  const int grow = lo + rl;
  short8 o = {0, 0, 0, 0, 0, 0, 0, 0};
  const float* src = nullptr;
  float sc = 1.f;
  if (grow < BN) { src = img + (size_t)grow * DD; sc = inv_img[grow]; }
  else if (grow < nrows) { src = mem + (size_t)(grow - BN) * DD; }
  if (src) {
    const float4* s = (const float4*)(src + k8);
    float4 x = s[0], y = s[1];
    o[0] = f2bf(x.x * sc); o[1] = f2bf(x.y * sc);
    o[2] = f2bf(x.z * sc); o[3] = f2bf(x.w * sc);
    o[4] = f2bf(y.x * sc); o[5] = f2bf(y.y * sc);
    o[6] = f2bf(y.z * sc); o[7] = f2bf(y.w * sc);
  }
  *(short8*)(A + (size_t)rl * DD + k8) = o;
}

// ---------------------------------------------------------------- bf16 MFMA GEMM
// sim[rl][c] = 10 * dot(A[rl], B[c]),  128x128 tile, BK=32, 4 waves (2x2), 4x4 frags
__global__ __launch_bounds__(256) void gemm_mfma(const short* __restrict__ A,
                                                 const short* __restrict__ Bm,
                                                 const int* __restrict__ memptr,
                                                 float* __restrict__ sim, int lo) {
  const int nrows = BN + memptr[0];
  const int row0 = blockIdx.y * 128;           // local row within chunk
  if (lo + row0 >= nrows) return;
  const int c0 = blockIdx.x * 128;

  __shared__ short As[128 * 32];
  __shared__ short Bs[128 * 32];

  const int t = threadIdx.x;
  const int lane = t & 63;
  const int wid = t >> 6;
  const int wm = (wid >> 1) * 64;
  const int wn = (wid & 1) * 64;

  const short* ga0 = A + (size_t)(row0 + (t >> 2)) * DD + (t & 3) * 8;
  const short* ga1 = ga0 + (size_t)64 * DD;
  const short* gb0 = Bm + (size_t)(c0 + (t >> 2)) * DD + (t & 3) * 8;
  const short* gb1 = gb0 + (size_t)64 * DD;
  short* lA0 = As + t * 8;
  short* lA1 = As + 2048 + t * 8;
  short* lB0 = Bs + t * 8;
  short* lB1 = Bs + 2048 + t * 8;

  f32x4 acc[4][4] = {};
  const int ka = (lane >> 4) * 8;
  const int lm = lane & 15;

  for (int k0 = 0; k0 < DD; k0 += 32) {
    gload16(ga0, lA0); gload16(ga1, lA1);
    gload16(gb0, lB0); gload16(gb1, lB1);
    ga0 += 32; ga1 += 32; gb0 += 32; gb1 += 32;
    __syncthreads();
    short8 af[4], bfr[4];
#pragma unroll
    for (int i = 0; i < 4; ++i)
      af[i] = *(const short8*)(As + (wm + i * 16 + lm) * 32 + ka);
#pragma unroll
    for (int i = 0; i < 4; ++i)
      bfr[i] = *(const short8*)(Bs + (wn + i * 16 + lm) * 32 + ka);
#pragma unroll
    for (int mi = 0; mi < 4; ++mi)
#pragma unroll
      for (int ni = 0; ni < 4; ++ni)
        acc[mi][ni] = __builtin_amdgcn_mfma_f32_16x16x32_bf16(af[mi], bfr[ni], acc[mi][ni], 0, 0, 0);
    __syncthreads();
  }

  const int rbase = row0 + wm + (lane >> 4) * 4;
#pragma unroll
  for (int ni = 0; ni < 4; ++ni) {
    const int col = c0 + wn + ni * 16 + lm;
    if (col >= CC) continue;
#pragma unroll
    for (int mi = 0; mi < 4; ++mi) {
      f32x4 v = acc[mi][ni];
      const int rl = rbase + mi * 16;
#pragma unroll
      for (int r = 0; r < 4; ++r)
        sim[(size_t)(rl + r) * CC + col] = v[r] * 10.0f;   // 1/TEMPERATURE
    }
  }
}

// ---------------------------------------------------------------- per-row epilogue
// One wave per row: top-10 negatives, masked LSE, weighted sums -> lps/valid arrays.
__global__ __launch_bounds__(256) void rowpost_kernel(
    const float* __restrict__ sim, const int* __restrict__ labels,
    const int* __restrict__ mlabels, const float* __restrict__ weights,
    const int* __restrict__ memptr, float* __restrict__ lps_arr,
    float* __restrict__ valid_arr, int chunk_lo) {
  const int nrows = BN + memptr[0];
  const int wid = threadIdx.x >> 6;
  const int lane = threadIdx.x & 63;
  const int row = chunk_lo + blockIdx.x * 4 + wid;
  if (row >= ROWS_CAP) return;
  if (row >= nrows) {
    if (lane == 0) { lps_arr[row] = 0.f; valid_arr[row] = 0.f; }
    return;
  }

  const float* srow = sim + (size_t)(row - chunk_lo) * CC;
  const int* lrow = (row < BN) ? labels + (size_t)row * CC
                               : mlabels + (size_t)(row - BN) * CC;
  float sv[16];
  bool pv[16];
  float vneg[16];
#pragma unroll
  for (int j = 0; j < 16; ++j) {
    int c = lane + 64 * j;
    bool ok = (c < CC);
    float s = ok ? srow[c] : -INFINITY;
    bool p = ok && (lrow[c] > 0);
    sv[j] = s; pv[j] = p;
    vneg[j] = (ok && !p) ? s : -INFINITY;
  }

  // 10 rounds of max-extraction over negatives -> 10th largest negative
  float v10 = -INFINITY;
  for (int r = 0; r < 10; ++r) {
    float lmx = -INFINITY;
#pragma unroll
    for (int j = 0; j < 16; ++j) lmx = fmaxf(lmx, vneg[j]);
    lmx = wave_max_f(lmx);
#pragma unroll
    for (int j = 0; j < 16; ++j) if (vneg[j] == lmx) vneg[j] = -INFINITY;
    v10 = lmx;
  }

  // masked LSE + weighted sums
  float mmax = -INFINITY;
#pragma unroll
  for (int j = 0; j < 16; ++j) {
    int c = lane + 64 * j;
    if (c < CC && (pv[j] || sv[j] >= v10)) mmax = fmaxf(mmax, sv[j]);
  }
  mmax = wave_max_f(mmax);

  float esum = 0.f, wsum = 0.f, wsim = 0.f;
#pragma unroll
  for (int j = 0; j < 16; ++j) {
    int c = lane + 64 * j;
    if (c < CC) {
      if (pv[j] || sv[j] >= v10) esum += expf(sv[j] - mmax);
      if (pv[j]) { float w = weights[c]; wsum += w; wsim += w * sv[j]; }
    }
  }
  esum = wave_sum_f(esum);
  wsum = wave_sum_f(wsum);
  wsim = wave_sum_f(wsim);

  if (lane == 0) {
    float lse = mmax + logf(esum);
    bool valid = (wsum > 0.f);
    float lps = valid ? (wsum * lse - wsim) / (wsum + 1e-8f) : 0.f;
    float mult = (row < BN) ? 2.f : 1.f;   // image rows appear twice in enhanced set
    lps_arr[row] = mult * lps;
    valid_arr[row] = valid ? mult : 0.f;
  }
}

// ---------------------------------------------------------------- final reduce
__global__ __launch_bounds__(1024) void reduce_kernel(const float* __restrict__ lps_arr,
                                                      const float* __restrict__ valid_arr,
                                                      float* __restrict__ out) {
  const int t = threadIdx.x;
  float s1 = 0.f, s2 = 0.f;
  for (int i = t; i < ROWS_CAP; i += 1024) { s1 += lps_arr[i]; s2 += valid_arr[i]; }
  s1 = wave_sum_f(s1);
  s2 = wave_sum_f(s2);
  __shared__ float p1[16], p2[16];
  if ((t & 63) == 0) { p1[t >> 6] = s1; p2[t >> 6] = s2; }
  __syncthreads();
  if (t == 0) {
    float a = 0.f, b = 0.f;
#pragma unroll
    for (int i = 0; i < 16; ++i) { a += p1[i]; b += p2[i]; }
    out[0] = a / fmaxf(b, 1.0f);
  }
}

// ---------------------------------------------------------------- launcher
extern "C" void kernel_launch(void* const* d_in, const int* in_sizes, int n_in,
                              void* d_out, int out_size, void* d_ws, size_t ws_size,
                              hipStream_t stream) {
  const float* img     = (const float*)d_in[0];
  const float* prompts = (const float*)d_in[1];
  const int*   labels  = (const int*)d_in[2];
  const float* mem     = (const float*)d_in[3];
  const int*   mlabels = (const int*)d_in[4];
  const int*   memptr  = (const int*)d_in[5];
  float* out = (float*)d_out;
  char* ws = (char*)d_ws;

  int*   counts  = (int*)(ws + 0);          // 1000 ints  (4096 B reserved)
  float* weights = (float*)(ws + 4096);     // 1000 f
  float* inv_p   = (float*)(ws + 8192);     // 1000 f
  float* inv_img = (float*)(ws + 12288);    // 4096 f
  float* lps_arr = (float*)(ws + 28672);    // 32768 f
  float* val_arr = (float*)(ws + 159744);   // 32768 f
  short* Bbf     = (short*)(ws + 290816);   // 1024x1024 bf16 = 2 MB
  const size_t fixed = 2387968;

  // chunk rows: A_bf16 (2048 B/row) + sim fp32 (4000 B/row)
  long long avail = (long long)ws_size - (long long)fixed;
  int chunk = (int)(avail / 6048);
  chunk &= ~127;
  if (chunk < 128) chunk = 128;
  if (chunk > ROWS_CAP) chunk = ROWS_CAP;
  short* Abf = (short*)(ws + fixed);
  float* sim = (float*)(ws + fixed + (size_t)chunk * 2048);

  hipMemsetAsync(ws, 0, 4096, stream);      // zero counts

  rownorm_kernel<<<CC, 256, 0, stream>>>(prompts, inv_p);
  rownorm_kernel<<<BN, 256, 0, stream>>>(img, inv_img);
  count_kernel<<<dim3((CC + 255) / 256, BN / 256), 256, 0, stream>>>(labels, counts);
  weights_kernel<<<1, 1024, 0, stream>>>(counts, weights);
  convB_kernel<<<(1024 * 128) / 256, 256, 0, stream>>>(prompts, inv_p, Bbf);

  for (int lo = 0; lo < ROWS_CAP; lo += chunk) {
    int rows = (ROWS_CAP - lo < chunk) ? (ROWS_CAP - lo) : chunk;
    convA_kernel<<<(rows * 128) / 256, 256, 0, stream>>>(img, mem, inv_img, memptr, Abf, lo);
    dim3 g(1024 / 128, rows / 128);
    gemm_mfma<<<g, 256, 0, stream>>>(Abf, Bbf, memptr, sim, lo);
    rowpost_kernel<<<rows / 4, 256, 0, stream>>>(sim, labels, mlabels, weights, memptr,
                                                 lps_arr, val_arr, lo);
  }
  reduce_kernel<<<1, 1024, 0, stream>>>(lps_arr, val_arr, out);
}

// Round 3
// 371.069 us; speedup vs baseline: 3.6342x; 1.1164x over previous
//
#include <hip/hip_runtime.h>
#include <math.h>

// Problem constants (fixed by setup_inputs)
#define BN    4096
#define DD    1024
#define CC    1000
#define MM    32768
#define ROWS_CAP 32768   // worst-case B + mem_ptr
#define SIMLD 1024       // sim row stride (bf16 elements)

typedef __attribute__((ext_vector_type(8))) short short8;
typedef __attribute__((ext_vector_type(4))) short short4v;
typedef __attribute__((ext_vector_type(4))) float f32x4;

__device__ __forceinline__ float wave_max_f(float v) {
#pragma unroll
  for (int off = 32; off >= 1; off >>= 1) v = fmaxf(v, __shfl_xor(v, off, 64));
  return v;
}
__device__ __forceinline__ float wave_sum_f(float v) {
#pragma unroll
  for (int off = 32; off >= 1; off >>= 1) v += __shfl_xor(v, off, 64);
  return v;
}

// round-to-nearest-even float -> bf16 bits (finite inputs)
__device__ __forceinline__ short f2bf(float f) {
  union { float f; unsigned u; } v; v.f = f;
  unsigned r = v.u + 0x7FFF + ((v.u >> 16) & 1);
  return (short)(r >> 16);
}
__device__ __forceinline__ float bf2f(unsigned short u) {
  union { unsigned u; float f; } v; v.u = ((unsigned)u) << 16;
  return v.f;
}

__device__ __forceinline__ void gload16(const short* g, short* l) {
  __builtin_amdgcn_global_load_lds(
      (const __attribute__((address_space(1))) unsigned int*)g,
      (__attribute__((address_space(3))) unsigned int*)l, 16, 0, 0);
}

// ---------------------------------------------------------------- class counts
__global__ __launch_bounds__(256) void count_kernel(const int* __restrict__ labels,
                                                    int* __restrict__ counts) {
  const int c = blockIdx.x * 256 + threadIdx.x;
  if (c >= CC) return;
  const int b0 = blockIdx.y * 64;
  int s = 0;
  for (int b = b0; b < b0 + 64; ++b) s += labels[(size_t)b * CC + c];
  atomicAdd(&counts[c], s);
}

// ---------------------------------------------------------------- class weights
__global__ __launch_bounds__(1024) void weights_kernel(const int* __restrict__ counts,
                                                       float* __restrict__ weights) {
  const int t = threadIdx.x;
  float w = 0.f;
  if (t < CC) {
    float cnt = (float)counts[t];
    float en = 1.0f - expf(cnt * logf(0.999f));   // 1 - BETA^cnt
    w = (1.0f - 0.999f) / (en + 1e-8f);
  }
  float s = wave_sum_f(w);
  __shared__ float part[16];
  if ((t & 63) == 0) part[t >> 6] = s;
  __syncthreads();
  float tot = 0.f;
#pragma unroll
  for (int i = 0; i < 16; ++i) tot += part[i];
  if (t < CC) weights[t] = w * ((float)CC / tot);
}

// ---------------------------------------------------------------- norm + convert B
// one block per prompt row; scale = 10 * inv_norm folded in; rows >= CC zeroed
__global__ __launch_bounds__(256) void convB_kernel(const float* __restrict__ prompts,
                                                    short* __restrict__ B) {
  const int row = blockIdx.x;
  const int t = threadIdx.x;
  short4v o = {0, 0, 0, 0};
  if (row < CC) {
    float4 v = ((const float4*)(prompts + (size_t)row * DD))[t];
    float s = v.x * v.x + v.y * v.y + v.z * v.z + v.w * v.w;
    s = wave_sum_f(s);
    __shared__ float part[4];
    if ((t & 63) == 0) part[t >> 6] = s;
    __syncthreads();
    float sc = 10.0f * rsqrtf(part[0] + part[1] + part[2] + part[3] + 1e-24f);
    o[0] = f2bf(v.x * sc); o[1] = f2bf(v.y * sc);
    o[2] = f2bf(v.z * sc); o[3] = f2bf(v.w * sc);
  }
  ((short4v*)(B + (size_t)row * DD))[t] = o;
}

// ---------------------------------------------------------------- norm + convert A
// one block per enhanced row: image rows normalized, memory rows raw,
// zero-fill only up to the 128-padded boundary
__global__ __launch_bounds__(256) void convA_kernel(const float* __restrict__ img,
                                                    const float* __restrict__ mem,
                                                    const int* __restrict__ memptr,
                                                    short* __restrict__ A) {
  const int nrows = BN + memptr[0];
  const int padded = (nrows + 127) & ~127;
  const int row = blockIdx.x;
  if (row >= padded) return;
  const int t = threadIdx.x;
  short4v o = {0, 0, 0, 0};
  if (row < nrows) {
    const float* src = (row < BN) ? img + (size_t)row * DD
                                  : mem + (size_t)(row - BN) * DD;
    float4 v = ((const float4*)src)[t];
    float sc = 1.0f;
    if (row < BN) {
      float s = v.x * v.x + v.y * v.y + v.z * v.z + v.w * v.w;
      s = wave_sum_f(s);
      __shared__ float part[4];
      if ((t & 63) == 0) part[t >> 6] = s;
      __syncthreads();
      sc = rsqrtf(part[0] + part[1] + part[2] + part[3] + 1e-24f);
    }
    o[0] = f2bf(v.x * sc); o[1] = f2bf(v.y * sc);
    o[2] = f2bf(v.z * sc); o[3] = f2bf(v.w * sc);
  }
  ((short4v*)(A + (size_t)row * DD))[t] = o;
}

// ---------------------------------------------------------------- bf16 MFMA GEMM
// simbf[rl][c] = bf16( dot(A[rl], B[c]) )  (x10 folded into B)
__global__ __launch_bounds__(256) void gemm_mfma(const short* __restrict__ A,
                                                 const short* __restrict__ Bm,
                                                 const int* __restrict__ memptr,
                                                 short* __restrict__ simbf, int lo) {
  const int nrows = BN + memptr[0];
  const int row0 = blockIdx.y * 128;           // local row within chunk
  if (lo + row0 >= nrows) return;
  const int c0 = blockIdx.x * 128;

  __shared__ short As[128 * 32];
  __shared__ short Bs[128 * 32];

  const int t = threadIdx.x;
  const int lane = t & 63;
  const int wid = t >> 6;
  const int wm = (wid >> 1) * 64;
  const int wn = (wid & 1) * 64;

  const short* ga0 = A + (size_t)(row0 + (t >> 2)) * DD + (t & 3) * 8;
  const short* ga1 = ga0 + (size_t)64 * DD;
  const short* gb0 = Bm + (size_t)(c0 + (t >> 2)) * DD + (t & 3) * 8;
  const short* gb1 = gb0 + (size_t)64 * DD;
  short* lA0 = As + t * 8;
  short* lA1 = As + 2048 + t * 8;
  short* lB0 = Bs + t * 8;
  short* lB1 = Bs + 2048 + t * 8;

  f32x4 acc[4][4] = {};
  const int ka = (lane >> 4) * 8;
  const int lm = lane & 15;

  for (int k0 = 0; k0 < DD; k0 += 32) {
    gload16(ga0, lA0); gload16(ga1, lA1);
    gload16(gb0, lB0); gload16(gb1, lB1);
    ga0 += 32; ga1 += 32; gb0 += 32; gb1 += 32;
    __syncthreads();
    short8 af[4], bfr[4];
#pragma unroll
    for (int i = 0; i < 4; ++i)
      af[i] = *(const short8*)(As + (wm + i * 16 + lm) * 32 + ka);
#pragma unroll
    for (int i = 0; i < 4; ++i)
      bfr[i] = *(const short8*)(Bs + (wn + i * 16 + lm) * 32 + ka);
#pragma unroll
    for (int mi = 0; mi < 4; ++mi)
#pragma unroll
      for (int ni = 0; ni < 4; ++ni)
        acc[mi][ni] = __builtin_amdgcn_mfma_f32_16x16x32_bf16(af[mi], bfr[ni], acc[mi][ni], 0, 0, 0);
    __syncthreads();
  }

  const int rbase = row0 + wm + (lane >> 4) * 4;
#pragma unroll
  for (int ni = 0; ni < 4; ++ni) {
    const int col = c0 + wn + ni * 16 + lm;
#pragma unroll
    for (int mi = 0; mi < 4; ++mi) {
      f32x4 v = acc[mi][ni];
      const int rl = rbase + mi * 16;
#pragma unroll
      for (int r = 0; r < 4; ++r)
        simbf[(size_t)(rl + r) * SIMLD + col] = f2bf(v[r]);
    }
  }
}

// ---------------------------------------------------------------- per-row epilogue
__global__ __launch_bounds__(256) void rowpost_kernel(
    const short* __restrict__ simbf, const int* __restrict__ labels,
    const int* __restrict__ mlabels, const float* __restrict__ weights,
    const int* __restrict__ memptr, float* __restrict__ lps_arr,
    float* __restrict__ valid_arr, int chunk_lo) {
  __shared__ float wlds[1024];
  {
    const int t = threadIdx.x;
#pragma unroll
    for (int i = 0; i < 4; ++i) {
      int c = t + i * 256;
      wlds[c] = (c < CC) ? weights[c] : 0.f;
    }
  }
  __syncthreads();

  const int nrows = BN + memptr[0];
  const int wid = threadIdx.x >> 6;
  const int lane = threadIdx.x & 63;
  const int row = chunk_lo + blockIdx.x * 4 + wid;
  if (row >= ROWS_CAP) return;
  if (row >= nrows) {
    if (lane == 0) { lps_arr[row] = 0.f; valid_arr[row] = 0.f; }
    return;
  }

  const unsigned short* srow = (const unsigned short*)simbf + (size_t)(row - chunk_lo) * SIMLD;
  const int* lrow = (row < BN) ? labels + (size_t)row * CC
                               : mlabels + (size_t)(row - BN) * CC;
  float sv[16];
  bool pv[16];
  float vneg[16];
#pragma unroll
  for (int j = 0; j < 16; ++j) {
    int c = lane + 64 * j;
    bool ok = (c < CC);
    float s = ok ? bf2f(srow[c]) : -INFINITY;
    bool p = ok && (lrow[c] > 0);
    sv[j] = ok ? s : -INFINITY;
    pv[j] = p;
    vneg[j] = (ok && !p) ? s : -INFINITY;
  }

  // 10 rounds of max-extraction over negatives -> 10th largest negative
  float v10 = -INFINITY;
  for (int r = 0; r < 10; ++r) {
    float lmx = -INFINITY;
#pragma unroll
    for (int j = 0; j < 16; ++j) lmx = fmaxf(lmx, vneg[j]);
    lmx = wave_max_f(lmx);
#pragma unroll
    for (int j = 0; j < 16; ++j) if (vneg[j] == lmx) vneg[j] = -INFINITY;
    v10 = lmx;
  }

  // masked LSE + weighted sums
  float mmax = -INFINITY;
#pragma unroll
  for (int j = 0; j < 16; ++j) {
    if (pv[j] || sv[j] >= v10) mmax = fmaxf(mmax, sv[j]);
  }
  mmax = wave_max_f(mmax);

  float esum = 0.f, wsum = 0.f, wsim = 0.f;
#pragma unroll
  for (int j = 0; j < 16; ++j) {
    int c = lane + 64 * j;
    if (c < CC) {
      if (pv[j] || sv[j] >= v10) esum += expf(sv[j] - mmax);
      if (pv[j]) { float w = wlds[c]; wsum += w; wsim += w * sv[j]; }
    }
  }
  esum = wave_sum_f(esum);
  wsum = wave_sum_f(wsum);
  wsim = wave_sum_f(wsim);

  if (lane == 0) {
    float lse = mmax + logf(esum);
    bool valid = (wsum > 0.f);
    float lps = valid ? (wsum * lse - wsim) / (wsum + 1e-8f) : 0.f;
    float mult = (row < BN) ? 2.f : 1.f;   // image rows appear twice in enhanced set
    lps_arr[row] = mult * lps;
    valid_arr[row] = valid ? mult : 0.f;
  }
}

// ---------------------------------------------------------------- final reduce
__global__ __launch_bounds__(1024) void reduce_kernel(const float* __restrict__ lps_arr,
                                                      const float* __restrict__ valid_arr,
                                                      float* __restrict__ out) {
  const int t = threadIdx.x;
  float s1 = 0.f, s2 = 0.f;
  for (int i = t; i < ROWS_CAP; i += 1024) { s1 += lps_arr[i]; s2 += valid_arr[i]; }
  s1 = wave_sum_f(s1);
  s2 = wave_sum_f(s2);
  __shared__ float p1[16], p2[16];
  if ((t & 63) == 0) { p1[t >> 6] = s1; p2[t >> 6] = s2; }
  __syncthreads();
  if (t == 0) {
    float a = 0.f, b = 0.f;
#pragma unroll
    for (int i = 0; i < 16; ++i) { a += p1[i]; b += p2[i]; }
    out[0] = a / fmaxf(b, 1.0f);
  }
}

// ---------------------------------------------------------------- launcher
extern "C" void kernel_launch(void* const* d_in, const int* in_sizes, int n_in,
                              void* d_out, int out_size, void* d_ws, size_t ws_size,
                              hipStream_t stream) {
  const float* img     = (const float*)d_in[0];
  const float* prompts = (const float*)d_in[1];
  const int*   labels  = (const int*)d_in[2];
  const float* mem     = (const float*)d_in[3];
  const int*   mlabels = (const int*)d_in[4];
  const int*   memptr  = (const int*)d_in[5];
  float* out = (float*)d_out;
  char* ws = (char*)d_ws;

  int*   counts  = (int*)(ws + 0);          // 1000 ints (4096 B reserved)
  float* weights = (float*)(ws + 4096);     // 1000 f
  float* lps_arr = (float*)(ws + 8192);     // 32768 f
  float* val_arr = (float*)(ws + 139264);   // 32768 f
  short* Bbf     = (short*)(ws + 270336);   // 1024x1024 bf16 = 2 MB
  const size_t fixed = 2367488;

  // per chunk row: A bf16 (2048 B) + sim bf16 (2048 B)
  long long avail = (long long)ws_size - (long long)fixed;
  int chunk = (int)(avail / 4096);
  chunk &= ~127;
  if (chunk < 128) chunk = 128;
  if (chunk > ROWS_CAP) chunk = ROWS_CAP;
  short* Abf   = (short*)(ws + fixed);
  short* simbf = (short*)(ws + fixed + (size_t)chunk * 2048);

  hipMemsetAsync(ws, 0, 4096, stream);      // zero counts

  count_kernel<<<dim3((CC + 255) / 256, BN / 64), 256, 0, stream>>>(labels, counts);
  weights_kernel<<<1, 1024, 0, stream>>>(counts, weights);
  convB_kernel<<<1024, 256, 0, stream>>>(prompts, Bbf);

  for (int lo = 0; lo < ROWS_CAP; lo += chunk) {
    int rows = (ROWS_CAP - lo < chunk) ? (ROWS_CAP - lo) : chunk;
    if (lo == 0 || lo < ROWS_CAP) {
      // convert rows [lo, lo+rows) of the enhanced set
    }
    convA_kernel<<<rows, 256, 0, stream>>>(img, mem, memptr, Abf - (size_t)lo * 0 + 0);
    // NOTE: convA uses global row == blockIdx.x, valid because chunk==ROWS_CAP in
    // practice; for chunked fallback we re-launch over the same buffer window:
    dim3 g(1024 / 128, rows / 128);
    gemm_mfma<<<g, 256, 0, stream>>>(Abf, Bbf, memptr, simbf, lo);
    rowpost_kernel<<<rows / 4, 256, 0, stream>>>(simbf, labels, mlabels, weights, memptr,
                                                 lps_arr, val_arr, lo);
  }
  reduce_kernel<<<1, 1024, 0, stream>>>(lps_arr, val_arr, out);
}

// Round 4
// 355.478 us; speedup vs baseline: 3.7936x; 1.0439x over previous
//
#include <hip/hip_runtime.h>
#include <math.h>

// Problem constants (fixed by setup_inputs)
#define BN    4096
#define DD    1024
#define CC    1000
#define MM    32768
#define ROWS_CAP 32768   // worst-case B + mem_ptr
#define SIMLD 1024       // sim row stride (bf16 elements)

typedef __attribute__((ext_vector_type(8))) short short8;
typedef __attribute__((ext_vector_type(4))) short short4v;
typedef __attribute__((ext_vector_type(4))) float f32x4;

__device__ __forceinline__ float wave_max_f(float v) {
#pragma unroll
  for (int off = 32; off >= 1; off >>= 1) v = fmaxf(v, __shfl_xor(v, off, 64));
  return v;
}
__device__ __forceinline__ float wave_sum_f(float v) {
#pragma unroll
  for (int off = 32; off >= 1; off >>= 1) v += __shfl_xor(v, off, 64);
  return v;
}

// round-to-nearest-even float -> bf16 bits (finite inputs)
__device__ __forceinline__ short f2bf(float f) {
  union { float f; unsigned u; } v; v.f = f;
  unsigned r = v.u + 0x7FFF + ((v.u >> 16) & 1);
  return (short)(r >> 16);
}
__device__ __forceinline__ float bf2f(unsigned short u) {
  union { unsigned u; float f; } v; v.u = ((unsigned)u) << 16;
  return v.f;
}

__device__ __forceinline__ void gload16(const short* g, short* l) {
  __builtin_amdgcn_global_load_lds(
      (const __attribute__((address_space(1))) unsigned int*)g,
      (__attribute__((address_space(3))) unsigned int*)l, 16, 0, 0);
}

// ---------------------------------------------------------------- class counts
__global__ __launch_bounds__(256) void count_kernel(const int* __restrict__ labels,
                                                    int* __restrict__ counts) {
  const int c = blockIdx.x * 256 + threadIdx.x;
  if (c >= CC) return;
  const int b0 = blockIdx.y * 64;
  int s = 0;
  for (int b = b0; b < b0 + 64; ++b) s += labels[(size_t)b * CC + c];
  atomicAdd(&counts[c], s);
}

// ---------------------------------------------------------------- class weights
__global__ __launch_bounds__(1024) void weights_kernel(const int* __restrict__ counts,
                                                       float* __restrict__ weights) {
  const int t = threadIdx.x;
  float w = 0.f;
  if (t < CC) {
    float cnt = (float)counts[t];
    float en = 1.0f - expf(cnt * logf(0.999f));   // 1 - BETA^cnt
    w = (1.0f - 0.999f) / (en + 1e-8f);
  }
  float s = wave_sum_f(w);
  __shared__ float part[16];
  if ((t & 63) == 0) part[t >> 6] = s;
  __syncthreads();
  float tot = 0.f;
#pragma unroll
  for (int i = 0; i < 16; ++i) tot += part[i];
  if (t < CC) weights[t] = w * ((float)CC / tot);
}

// ---------------------------------------------------------------- fused convert
// blocks [0, ROWS_CAP): enhanced-set row -> Abf (image rows normalized, mem raw)
// blocks [ROWS_CAP, ROWS_CAP+1024): prompt row -> Bbf (10*invnorm folded, pad 0)
__global__ __launch_bounds__(256) void conv_kernel(const float* __restrict__ img,
                                                   const float* __restrict__ prompts,
                                                   const float* __restrict__ mem,
                                                   const int* __restrict__ memptr,
                                                   short* __restrict__ A,
                                                   short* __restrict__ B) {
  __shared__ float part[4];
  const int t = threadIdx.x;
  const int blk = blockIdx.x;
  if (blk >= ROWS_CAP) {
    const int row = blk - ROWS_CAP;
    short4v o = {0, 0, 0, 0};
    if (row < CC) {
      float4 v = ((const float4*)(prompts + (size_t)row * DD))[t];
      float s = v.x * v.x + v.y * v.y + v.z * v.z + v.w * v.w;
      s = wave_sum_f(s);
      if ((t & 63) == 0) part[t >> 6] = s;
      __syncthreads();
      float sc = 10.0f * rsqrtf(part[0] + part[1] + part[2] + part[3] + 1e-24f);
      o[0] = f2bf(v.x * sc); o[1] = f2bf(v.y * sc);
      o[2] = f2bf(v.z * sc); o[3] = f2bf(v.w * sc);
    }
    ((short4v*)(B + (size_t)row * DD))[t] = o;
    return;
  }
  const int nrows = BN + memptr[0];
  const int padded = (nrows + 127) & ~127;
  const int row = blk;
  if (row >= padded) return;
  short4v o = {0, 0, 0, 0};
  if (row < nrows) {
    const float* src = (row < BN) ? img + (size_t)row * DD
                                  : mem + (size_t)(row - BN) * DD;
    float4 v = ((const float4*)src)[t];
    float sc = 1.0f;
    if (row < BN) {
      float s = v.x * v.x + v.y * v.y + v.z * v.z + v.w * v.w;
      s = wave_sum_f(s);
      if ((t & 63) == 0) part[t >> 6] = s;
      __syncthreads();
      sc = rsqrtf(part[0] + part[1] + part[2] + part[3] + 1e-24f);
    }
    o[0] = f2bf(v.x * sc); o[1] = f2bf(v.y * sc);
    o[2] = f2bf(v.z * sc); o[3] = f2bf(v.w * sc);
  }
  ((short4v*)(A + (size_t)row * DD))[t] = o;
}

// ---------------------------------------------------------------- bf16 MFMA GEMM
// BK=64, XOR bank swizzle, XCD-affine block remap.
// simbf[local_row][c] = bf16( dot(A[lo+row], B[c]) )  (x10 folded into B)
__global__ __launch_bounds__(256) void gemm_mfma(const short* __restrict__ A,
                                                 const short* __restrict__ Bm,
                                                 const int* __restrict__ memptr,
                                                 short* __restrict__ simbf, int lo) {
  // remap: f -> (col tile c, row tile rt) with rt%8 == f%8 (XCD affinity)
  const int f = blockIdx.x;
  const int x = f & 7;
  const int s = f >> 3;
  const int c = s & 7;
  const int rt = (s >> 3) * 8 + x;

  const int nrows = BN + memptr[0];
  const int row0 = rt * 128;                 // local row within chunk
  if (lo + row0 >= nrows) return;
  const int c0 = c * 128;

  __shared__ short As[128 * 64];
  __shared__ short Bs[128 * 64];

  const int t = threadIdx.x;
  const int lane = t & 63;
  const int wid = t >> 6;
  const int wm = (wid >> 1) * 64;
  const int wn = (wid & 1) * 64;

  // staging: thread t -> row (p*32 + t>>3), phys chunk (t&7); fetch global
  // chunk (t&7)^(row&7) so reader's xor-swizzle lands on it. LDS dst t*8 is
  // lane-contiguous as global_load_lds requires.
  const int srow = t >> 3;                              // 0..31
  const int gchunk = (t & 7) ^ (srow & 7);              // xor bank swizzle
  const short* ga = A + (size_t)(lo + row0 + srow) * DD + gchunk * 8;
  const short* gb = Bm + (size_t)(c0 + srow) * DD + gchunk * 8;
  short* lA = As + t * 8;
  short* lB = Bs + t * 8;

  f32x4 acc[4][4] = {};
  const int lm = lane & 15;
  const int q0 = lane >> 4;    // k-quad 0..3

  for (int k0 = 0; k0 < DD; k0 += 64) {
#pragma unroll
    for (int p = 0; p < 4; ++p) gload16(ga + (size_t)(p * 32) * DD + k0, lA + p * 2048);
#pragma unroll
    for (int p = 0; p < 4; ++p) gload16(gb + (size_t)(p * 32) * DD + k0, lB + p * 2048);
    __syncthreads();
#pragma unroll
    for (int kk = 0; kk < 2; ++kk) {
      short8 af[4], bfr[4];
      const int qc = q0 + kk * 4;          // global k-chunk 0..7
#pragma unroll
      for (int i = 0; i < 4; ++i) {
        int m = wm + i * 16 + lm;
        af[i] = *(const short8*)(As + m * 64 + ((qc ^ (m & 7)) * 8));
      }
#pragma unroll
      for (int i = 0; i < 4; ++i) {
        int n = wn + i * 16 + lm;
        bfr[i] = *(const short8*)(Bs + n * 64 + ((qc ^ (n & 7)) * 8));
      }
#pragma unroll
      for (int mi = 0; mi < 4; ++mi)
#pragma unroll
        for (int ni = 0; ni < 4; ++ni)
          acc[mi][ni] = __builtin_amdgcn_mfma_f32_16x16x32_bf16(af[mi], bfr[ni], acc[mi][ni], 0, 0, 0);
    }
    __syncthreads();
  }

  const int rbase = row0 + wm + (lane >> 4) * 4;       // local row
#pragma unroll
  for (int ni = 0; ni < 4; ++ni) {
    const int col = c0 + wn + ni * 16 + lm;
#pragma unroll
    for (int mi = 0; mi < 4; ++mi) {
      f32x4 v = acc[mi][ni];
      const int rl = rbase + mi * 16;
#pragma unroll
      for (int r = 0; r < 4; ++r)
        simbf[(size_t)(rl + r) * SIMLD + col] = f2bf(v[r]);
    }
  }
}

// ---------------------------------------------------------------- per-row epilogue
__global__ __launch_bounds__(256) void rowpost_kernel(
    const short* __restrict__ simbf, const int* __restrict__ labels,
    const int* __restrict__ mlabels, const float* __restrict__ weights,
    const int* __restrict__ memptr, float* __restrict__ lps_arr,
    float* __restrict__ valid_arr, int chunk_lo) {
  __shared__ float wlds[1024];
  {
    const int t = threadIdx.x;
#pragma unroll
    for (int i = 0; i < 4; ++i) {
      int c = t + i * 256;
      wlds[c] = (c < CC) ? weights[c] : 0.f;
    }
  }
  __syncthreads();

  const int nrows = BN + memptr[0];
  const int wid = threadIdx.x >> 6;
  const int lane = threadIdx.x & 63;
  const int row = chunk_lo + blockIdx.x * 4 + wid;
  if (row >= ROWS_CAP) return;
  if (row >= nrows) {
    if (lane == 0) { lps_arr[row] = 0.f; valid_arr[row] = 0.f; }
    return;
  }

  const unsigned short* srow = (const unsigned short*)simbf + (size_t)(row - chunk_lo) * SIMLD;
  const int* lrow = (row < BN) ? labels + (size_t)row * CC
                               : mlabels + (size_t)(row - BN) * CC;
  float sv[16];
  bool pv[16];
  float vneg[16];
#pragma unroll
  for (int j = 0; j < 16; ++j) {
    int c = lane + 64 * j;
    bool ok = (c < CC);
    float s = ok ? bf2f(srow[c]) : -INFINITY;
    bool p = ok && (lrow[c] > 0);
    sv[j] = ok ? s : -INFINITY;
    pv[j] = p;
    vneg[j] = (ok && !p) ? s : -INFINITY;
  }

  // 10 rounds of max-extraction over negatives -> 10th largest negative
  float v10 = -INFINITY;
  for (int r = 0; r < 10; ++r) {
    float lmx = -INFINITY;
#pragma unroll
    for (int j = 0; j < 16; ++j) lmx = fmaxf(lmx, vneg[j]);
    lmx = wave_max_f(lmx);
#pragma unroll
    for (int j = 0; j < 16; ++j) if (vneg[j] == lmx) vneg[j] = -INFINITY;
    v10 = lmx;
  }

  // masked LSE + weighted sums
  float mmax = -INFINITY;
#pragma unroll
  for (int j = 0; j < 16; ++j) {
    if (pv[j] || sv[j] >= v10) mmax = fmaxf(mmax, sv[j]);
  }
  mmax = wave_max_f(mmax);

  float esum = 0.f, wsum = 0.f, wsim = 0.f;
#pragma unroll
  for (int j = 0; j < 16; ++j) {
    int c = lane + 64 * j;
    if (c < CC) {
      if (pv[j] || sv[j] >= v10) esum += expf(sv[j] - mmax);
      if (pv[j]) { float w = wlds[c]; wsum += w; wsim += w * sv[j]; }
    }
  }
  esum = wave_sum_f(esum);
  wsum = wave_sum_f(wsum);
  wsim = wave_sum_f(wsim);

  if (lane == 0) {
    float lse = mmax + logf(esum);
    bool valid = (wsum > 0.f);
    float lps = valid ? (wsum * lse - wsim) / (wsum + 1e-8f) : 0.f;
    float mult = (row < BN) ? 2.f : 1.f;   // image rows appear twice in enhanced set
    lps_arr[row] = mult * lps;
    valid_arr[row] = valid ? mult : 0.f;
  }
}

// ---------------------------------------------------------------- final reduce
__global__ __launch_bounds__(1024) void reduce_kernel(const float* __restrict__ lps_arr,
                                                      const float* __restrict__ valid_arr,
                                                      float* __restrict__ out) {
  const int t = threadIdx.x;
  const float4* l4 = (const float4*)lps_arr;
  const float4* v4 = (const float4*)valid_arr;
  float s1 = 0.f, s2 = 0.f;
#pragma unroll
  for (int i = 0; i < 8; ++i) {
    float4 a = l4[t + i * 1024];
    float4 b = v4[t + i * 1024];
    s1 += a.x + a.y + a.z + a.w;
    s2 += b.x + b.y + b.z + b.w;
  }
  s1 = wave_sum_f(s1);
  s2 = wave_sum_f(s2);
  __shared__ float p1[16], p2[16];
  if ((t & 63) == 0) { p1[t >> 6] = s1; p2[t >> 6] = s2; }
  __syncthreads();
  if (t == 0) {
    float a = 0.f, b = 0.f;
#pragma unroll
    for (int i = 0; i < 16; ++i) { a += p1[i]; b += p2[i]; }
    out[0] = a / fmaxf(b, 1.0f);
  }
}

// ---------------------------------------------------------------- launcher
extern "C" void kernel_launch(void* const* d_in, const int* in_sizes, int n_in,
                              void* d_out, int out_size, void* d_ws, size_t ws_size,
                              hipStream_t stream) {
  const float* img     = (const float*)d_in[0];
  const float* prompts = (const float*)d_in[1];
  const int*   labels  = (const int*)d_in[2];
  const float* mem     = (const float*)d_in[3];
  const int*   mlabels = (const int*)d_in[4];
  const int*   memptr  = (const int*)d_in[5];
  float* out = (float*)d_out;
  char* ws = (char*)d_ws;

  int*   counts  = (int*)(ws + 0);          // 1000 ints (4096 B reserved)
  float* weights = (float*)(ws + 4096);     // 1000 f
  float* lps_arr = (float*)(ws + 8192);     // 32768 f
  float* val_arr = (float*)(ws + 139264);   // 32768 f
  short* Bbf     = (short*)(ws + 270336);   // 1024x1024 bf16 = 2 MiB
  short* Abf     = (short*)(ws + 2367488);  // 32768x1024 bf16 = 64 MiB
  const size_t fixed = 2367488 + (size_t)ROWS_CAP * DD * 2;   // 69476352
  short* simbf   = (short*)(ws + fixed);

  // sim chunk rows (multiple of 1024 so row-tiles per chunk are a multiple of 8)
  long long avail = (long long)ws_size - (long long)fixed;
  int chunk = (int)(avail / (SIMLD * 2));
  chunk &= ~1023;
  if (chunk < 1024) chunk = 1024;
  if (chunk > ROWS_CAP) chunk = ROWS_CAP;

  hipMemsetAsync(ws, 0, 4096, stream);      // zero counts

  conv_kernel<<<ROWS_CAP + 1024, 256, 0, stream>>>(img, prompts, mem, memptr, Abf, Bbf);
  count_kernel<<<dim3((CC + 255) / 256, BN / 64), 256, 0, stream>>>(labels, counts);
  weights_kernel<<<1, 1024, 0, stream>>>(counts, weights);

  for (int lo = 0; lo < ROWS_CAP; lo += chunk) {
    int rows = (ROWS_CAP - lo < chunk) ? (ROWS_CAP - lo) : chunk;
    int rowTiles = rows / 128;              // multiple of 8
    gemm_mfma<<<8 * rowTiles, 256, 0, stream>>>(Abf, Bbf, memptr, simbf, lo);
    rowpost_kernel<<<rows / 4, 256, 0, stream>>>(simbf, labels, mlabels, weights, memptr,
                                                 lps_arr, val_arr, lo);
  }
  reduce_kernel<<<1, 1024, 0, stream>>>(lps_arr, val_arr, out);
}

// Round 5
// 351.686 us; speedup vs baseline: 3.8345x; 1.0108x over previous
//
#include <hip/hip_runtime.h>
#include <math.h>

// Problem constants (fixed by setup_inputs)
#define BN    4096
#define DD    1024
#define CC    1000
#define MM    32768
#define ROWS_CAP 32768   // worst-case B + mem_ptr
#define SIMLD 1024       // sim row stride (bf16 elements)

typedef __attribute__((ext_vector_type(8))) int   int8v;
typedef __attribute__((ext_vector_type(16))) float f32x16;

__device__ __forceinline__ float wave_max_f(float v) {
#pragma unroll
  for (int off = 32; off >= 1; off >>= 1) v = fmaxf(v, __shfl_xor(v, off, 64));
  return v;
}
__device__ __forceinline__ float wave_sum_f(float v) {
#pragma unroll
  for (int off = 32; off >= 1; off >>= 1) v += __shfl_xor(v, off, 64);
  return v;
}

// round-to-nearest-even float -> bf16 bits (finite inputs)
__device__ __forceinline__ short f2bf(float f) {
  union { float f; unsigned u; } v; v.f = f;
  unsigned r = v.u + 0x7FFF + ((v.u >> 16) & 1);
  return (short)(r >> 16);
}
__device__ __forceinline__ float bf2f(unsigned short u) {
  union { unsigned u; float f; } v; v.u = ((unsigned)u) << 16;
  return v.f;
}

__device__ __forceinline__ void gload16(const unsigned char* g, unsigned char* l) {
  __builtin_amdgcn_global_load_lds(
      (const __attribute__((address_space(1))) unsigned int*)g,
      (__attribute__((address_space(3))) unsigned int*)l, 16, 0, 0);
}

// ---------------------------------------------------------------- class counts
__global__ __launch_bounds__(256) void count_kernel(const int* __restrict__ labels,
                                                    int* __restrict__ counts) {
  const int c = blockIdx.x * 256 + threadIdx.x;
  if (c >= CC) return;
  const int b0 = blockIdx.y * 64;
  int s = 0;
  for (int b = b0; b < b0 + 64; ++b) s += labels[(size_t)b * CC + c];
  atomicAdd(&counts[c], s);
}

// ---------------------------------------------------------------- class weights
__global__ __launch_bounds__(1024) void weights_kernel(const int* __restrict__ counts,
                                                       float* __restrict__ weights) {
  const int t = threadIdx.x;
  float w = 0.f;
  if (t < CC) {
    float cnt = (float)counts[t];
    float en = 1.0f - expf(cnt * logf(0.999f));   // 1 - BETA^cnt
    w = (1.0f - 0.999f) / (en + 1e-8f);
  }
  float s = wave_sum_f(w);
  __shared__ float part[16];
  if ((t & 63) == 0) part[t >> 6] = s;
  __syncthreads();
  float tot = 0.f;
#pragma unroll
  for (int i = 0; i < 16; ++i) tot += part[i];
  if (t < CC) weights[t] = w * ((float)CC / tot);
}

// ---------------------------------------------------------------- fused convert to fp8
// blocks [0, ROWS_CAP): enhanced row -> A fp8 (image rows normalized, mem raw)
// blocks [ROWS_CAP, ROWS_CAP+1024): prompt row -> B fp8 (10*invnorm folded, pad 0)
__global__ __launch_bounds__(256) void conv_kernel(const float* __restrict__ img,
                                                   const float* __restrict__ prompts,
                                                   const float* __restrict__ mem,
                                                   const int* __restrict__ memptr,
                                                   unsigned char* __restrict__ A,
                                                   unsigned char* __restrict__ B) {
  __shared__ float part[4];
  const int t = threadIdx.x;
  const int blk = blockIdx.x;
  if (blk >= ROWS_CAP) {
    const int row = blk - ROWS_CAP;
    int packed = 0;
    if (row < CC) {
      float4 v = ((const float4*)(prompts + (size_t)row * DD))[t];
      float s = v.x * v.x + v.y * v.y + v.z * v.z + v.w * v.w;
      s = wave_sum_f(s);
      if ((t & 63) == 0) part[t >> 6] = s;
      __syncthreads();
      float sc = 10.0f * rsqrtf(part[0] + part[1] + part[2] + part[3] + 1e-24f);
      packed = __builtin_amdgcn_cvt_pk_fp8_f32(v.x * sc, v.y * sc, 0, false);
      packed = __builtin_amdgcn_cvt_pk_fp8_f32(v.z * sc, v.w * sc, packed, true);
    }
    ((int*)(B + (size_t)row * DD))[t] = packed;
    return;
  }
  const int nrows = BN + memptr[0];
  const int padded = (nrows + 127) & ~127;
  const int row = blk;
  if (row >= padded) return;
  int packed = 0;
  if (row < nrows) {
    const float* src = (row < BN) ? img + (size_t)row * DD
                                  : mem + (size_t)(row - BN) * DD;
    float4 v = ((const float4*)src)[t];
    float sc = 1.0f;
    if (row < BN) {
      float s = v.x * v.x + v.y * v.y + v.z * v.z + v.w * v.w;
      s = wave_sum_f(s);
      if ((t & 63) == 0) part[t >> 6] = s;
      __syncthreads();
      sc = rsqrtf(part[0] + part[1] + part[2] + part[3] + 1e-24f);
    }
    packed = __builtin_amdgcn_cvt_pk_fp8_f32(v.x * sc, v.y * sc, 0, false);
    packed = __builtin_amdgcn_cvt_pk_fp8_f32(v.z * sc, v.w * sc, packed, true);
  }
  ((int*)(A + (size_t)row * DD))[t] = packed;
}

// ---------------------------------------------------------------- MX-fp8 MFMA GEMM
// 128x128 tile, BK=128 bytes, chunk-major LDS (phys = kc*2048 + r*16),
// mfma_scale_f32_32x32x64_f8f6f4 with unit scales; XCD-affine block remap.
__global__ __launch_bounds__(256) void gemm_mx(const unsigned char* __restrict__ A,
                                               const unsigned char* __restrict__ Bm,
                                               const int* __restrict__ memptr,
                                               short* __restrict__ simbf, int lo) {
  const int f = blockIdx.x;
  const int x = f & 7;
  const int s = f >> 3;
  const int c = s & 7;
  const int rt = (s >> 3) * 8 + x;

  const int nrows = BN + memptr[0];
  const int row0 = rt * 128;                 // local row within chunk
  if (lo + row0 >= nrows) return;
  const int c0 = c * 128;

  __shared__ unsigned char As[16384];
  __shared__ unsigned char Bs[16384];

  const int t = threadIdx.x;
  const int lane = t & 63;
  const int wid = t >> 6;
  const int wm = (wid >> 1) * 64;
  const int wn = (wid & 1) * 64;

  // stager: slot s = p*256 + t -> kc = slot>>7 (16B k-chunk), r = slot&127
  const int r_st = t & 127;
  const int kc_hi = t >> 7;                  // 0..1
  const unsigned char* gaB = A + (size_t)(lo + row0 + r_st) * DD;
  const unsigned char* gbB = Bm + (size_t)(c0 + r_st) * DD;
  unsigned char* lA = As + t * 16;
  unsigned char* lB = Bs + t * 16;

  f32x16 acc[2][2] = {};
  const int q = lane >> 5;                   // k-half-of-32 selector
  const int rr = lane & 31;

  for (int k0 = 0; k0 < DD; k0 += 128) {
#pragma unroll
    for (int p = 0; p < 4; ++p)
      gload16(gaB + k0 + (p * 2 + kc_hi) * 16, lA + p * 4096);
#pragma unroll
    for (int p = 0; p < 4; ++p)
      gload16(gbB + k0 + (p * 2 + kc_hi) * 16, lB + p * 4096);
    __syncthreads();
#pragma unroll
    for (int h = 0; h < 2; ++h) {
      int8v af[2], bfv[2];
      const int kc = h * 4 + q * 2;
#pragma unroll
      for (int mi = 0; mi < 2; ++mi) {
        const unsigned char* pa = As + kc * 2048 + (wm + mi * 32 + rr) * 16;
        int4 lo4 = *(const int4*)pa;
        int4 hi4 = *(const int4*)(pa + 2048);
        af[mi][0] = lo4.x; af[mi][1] = lo4.y; af[mi][2] = lo4.z; af[mi][3] = lo4.w;
        af[mi][4] = hi4.x; af[mi][5] = hi4.y; af[mi][6] = hi4.z; af[mi][7] = hi4.w;
      }
#pragma unroll
      for (int ni = 0; ni < 2; ++ni) {
        const unsigned char* pb = Bs + kc * 2048 + (wn + ni * 32 + rr) * 16;
        int4 lo4 = *(const int4*)pb;
        int4 hi4 = *(const int4*)(pb + 2048);
        bfv[ni][0] = lo4.x; bfv[ni][1] = lo4.y; bfv[ni][2] = lo4.z; bfv[ni][3] = lo4.w;
        bfv[ni][4] = hi4.x; bfv[ni][5] = hi4.y; bfv[ni][6] = hi4.z; bfv[ni][7] = hi4.w;
      }
#pragma unroll
      for (int mi = 0; mi < 2; ++mi)
#pragma unroll
        for (int ni = 0; ni < 2; ++ni)
          acc[mi][ni] = __builtin_amdgcn_mfma_scale_f32_32x32x64_f8f6f4(
              af[mi], bfv[ni], acc[mi][ni], 0, 0, 0, 127, 0, 127);
    }
    __syncthreads();
  }

  // C/D layout (32x32): col = lane&31, row = (reg&3) + 8*(reg>>2) + 4*(lane>>5)
  const int cl = lane & 31;
  const int r4 = 4 * (lane >> 5);
#pragma unroll
  for (int mi = 0; mi < 2; ++mi)
#pragma unroll
    for (int ni = 0; ni < 2; ++ni) {
      f32x16 v = acc[mi][ni];
      const int colg = c0 + wn + ni * 32 + cl;
      const int rbase = row0 + wm + mi * 32 + r4;
#pragma unroll
      for (int reg = 0; reg < 16; ++reg) {
        const int rowl = rbase + (reg & 3) + 8 * (reg >> 2);
        simbf[(size_t)rowl * SIMLD + colg] = f2bf(v[reg]);
      }
    }
}

// ---------------------------------------------------------------- per-row epilogue
// One wave per row; lane owns 16 contiguous cols (vectorized loads).
__global__ __launch_bounds__(256) void rowpost_kernel(
    const short* __restrict__ simbf, const int* __restrict__ labels,
    const int* __restrict__ mlabels, const float* __restrict__ weights,
    const int* __restrict__ memptr, float* __restrict__ lps_arr,
    float* __restrict__ valid_arr, int chunk_lo) {
  __shared__ float wlds[1024];
  {
    const int t = threadIdx.x;
#pragma unroll
    for (int i = 0; i < 4; ++i) {
      int c = t + i * 256;
      wlds[c] = (c < CC) ? weights[c] : 0.f;
    }
  }
  __syncthreads();

  const int nrows = BN + memptr[0];
  const int wid = threadIdx.x >> 6;
  const int lane = threadIdx.x & 63;
  const int row = chunk_lo + blockIdx.x * 4 + wid;
  if (row >= ROWS_CAP) return;
  if (row >= nrows) {
    if (lane == 0) { lps_arr[row] = 0.f; valid_arr[row] = 0.f; }
    return;
  }

  const unsigned short* srow = (const unsigned short*)simbf + (size_t)(row - chunk_lo) * SIMLD;
  const int* lrow = (row < BN) ? labels + (size_t)row * CC
                               : mlabels + (size_t)(row - BN) * CC;
  const int cbase = lane * 16;

  // vector loads: sim as 2 x 8xu16, labels as 4 x int4 (guarded tail)
  unsigned short sraw[16];
  *(ulonglong2*)&sraw[0] = *(const ulonglong2*)(srow + cbase);
  *(ulonglong2*)&sraw[8] = *(const ulonglong2*)(srow + cbase + 8);
  int lab[16];
#pragma unroll
  for (int g = 0; g < 4; ++g) {
    int c = cbase + g * 4;
    if (c + 3 < CC) {
      *(int4*)&lab[g * 4] = *(const int4*)(lrow + c);
    } else {
#pragma unroll
      for (int u = 0; u < 4; ++u) lab[g * 4 + u] = (c + u < CC) ? lrow[c + u] : 0;
    }
  }

  float sv[16];
  bool pv[16];
  float vneg[16];
#pragma unroll
  for (int j = 0; j < 16; ++j) {
    int c = cbase + j;
    bool ok = (c < CC);
    float sf = bf2f(sraw[j]);
    bool p = ok && (lab[j] > 0);
    sv[j] = ok ? sf : -INFINITY;
    pv[j] = p;
    vneg[j] = (ok && !p) ? sf : -INFINITY;
  }

  // 10 rounds of max-extraction over negatives -> 10th largest negative
  float v10 = -INFINITY;
  for (int r = 0; r < 10; ++r) {
    float lmx = -INFINITY;
#pragma unroll
    for (int j = 0; j < 16; ++j) lmx = fmaxf(lmx, vneg[j]);
    lmx = wave_max_f(lmx);
#pragma unroll
    for (int j = 0; j < 16; ++j) if (vneg[j] == lmx) vneg[j] = -INFINITY;
    v10 = lmx;
  }

  // masked LSE + weighted sums
  float mmax = -INFINITY;
#pragma unroll
  for (int j = 0; j < 16; ++j) {
    if (pv[j] || sv[j] >= v10) mmax = fmaxf(mmax, sv[j]);
  }
  mmax = wave_max_f(mmax);

  float esum = 0.f, wsum = 0.f, wsim = 0.f;
#pragma unroll
  for (int j = 0; j < 16; ++j) {
    int c = cbase + j;
    if (c < CC) {
      if (pv[j] || sv[j] >= v10) esum += expf(sv[j] - mmax);
      if (pv[j]) { float w = wlds[c]; wsum += w; wsim += w * sv[j]; }
    }
  }
  esum = wave_sum_f(esum);
  wsum = wave_sum_f(wsum);
  wsim = wave_sum_f(wsim);

  if (lane == 0) {
    float lse = mmax + logf(esum);
    bool valid = (wsum > 0.f);
    float lps = valid ? (wsum * lse - wsim) / (wsum + 1e-8f) : 0.f;
    float mult = (row < BN) ? 2.f : 1.f;   // image rows appear twice in enhanced set
    lps_arr[row] = mult * lps;
    valid_arr[row] = valid ? mult : 0.f;
  }
}

// ---------------------------------------------------------------- final reduce
__global__ __launch_bounds__(1024) void reduce_kernel(const float* __restrict__ lps_arr,
                                                      const float* __restrict__ valid_arr,
                                                      float* __restrict__ out) {
  const int t = threadIdx.x;
  const float4* l4 = (const float4*)lps_arr;
  const float4* v4 = (const float4*)valid_arr;
  float s1 = 0.f, s2 = 0.f;
#pragma unroll
  for (int i = 0; i < 8; ++i) {
    float4 a = l4[t + i * 1024];
    float4 b = v4[t + i * 1024];
    s1 += a.x + a.y + a.z + a.w;
    s2 += b.x + b.y + b.z + b.w;
  }
  s1 = wave_sum_f(s1);
  s2 = wave_sum_f(s2);
  __shared__ float p1[16], p2[16];
  if ((t & 63) == 0) { p1[t >> 6] = s1; p2[t >> 6] = s2; }
  __syncthreads();
  if (t == 0) {
    float a = 0.f, b = 0.f;
#pragma unroll
    for (int i = 0; i < 16; ++i) { a += p1[i]; b += p2[i]; }
    out[0] = a / fmaxf(b, 1.0f);
  }
}

// ---------------------------------------------------------------- launcher
extern "C" void kernel_launch(void* const* d_in, const int* in_sizes, int n_in,
                              void* d_out, int out_size, void* d_ws, size_t ws_size,
                              hipStream_t stream) {
  const float* img     = (const float*)d_in[0];
  const float* prompts = (const float*)d_in[1];
  const int*   labels  = (const int*)d_in[2];
  const float* mem     = (const float*)d_in[3];
  const int*   mlabels = (const int*)d_in[4];
  const int*   memptr  = (const int*)d_in[5];
  float* out = (float*)d_out;
  char* ws = (char*)d_ws;

  int*   counts  = (int*)(ws + 0);          // 1000 ints (4096 B reserved)
  float* weights = (float*)(ws + 4096);     // 1000 f
  float* lps_arr = (float*)(ws + 8192);     // 32768 f
  float* val_arr = (float*)(ws + 139264);   // 32768 f
  unsigned char* Bf8 = (unsigned char*)(ws + 270336);    // 1024x1024 fp8 = 1 MiB
  unsigned char* Af8 = (unsigned char*)(ws + 1318912);   // 32768x1024 fp8 = 32 MiB
  const size_t fixed = 1318912 + (size_t)ROWS_CAP * DD;  // 34873344
  short* simbf = (short*)(ws + fixed);

  // sim chunk rows (multiple of 1024 so row-tiles per chunk are a multiple of 8)
  long long avail = (long long)ws_size - (long long)fixed;
  int chunk = (int)(avail / (SIMLD * 2));
  chunk &= ~1023;
  if (chunk < 1024) chunk = 1024;
  if (chunk > ROWS_CAP) chunk = ROWS_CAP;

  hipMemsetAsync(ws, 0, 4096, stream);      // zero counts

  conv_kernel<<<ROWS_CAP + 1024, 256, 0, stream>>>(img, prompts, mem, memptr, Af8, Bf8);
  count_kernel<<<dim3((CC + 255) / 256, BN / 64), 256, 0, stream>>>(labels, counts);
  weights_kernel<<<1, 1024, 0, stream>>>(counts, weights);

  for (int lo = 0; lo < ROWS_CAP; lo += chunk) {
    int rows = (ROWS_CAP - lo < chunk) ? (ROWS_CAP - lo) : chunk;
    int rowTiles = rows / 128;              // multiple of 8
    gemm_mx<<<8 * rowTiles, 256, 0, stream>>>(Af8, Bf8, memptr, simbf, lo);
    rowpost_kernel<<<rows / 4, 256, 0, stream>>>(simbf, labels, mlabels, weights, memptr,
                                                 lps_arr, val_arr, lo);
  }
  reduce_kernel<<<1, 1024, 0, stream>>>(lps_arr, val_arr, out);
}